// Round 12
// baseline (201.476 us; speedup 1.0000x reference)
//
#include <hip/hip_runtime.h>
#include <hip/hip_bf16.h>
#include <math.h>

#define DI __device__ __forceinline__

static constexpr float SCALE = 0.17677669529663687f;  // 1/sqrt(32)

typedef short bf16x8 __attribute__((ext_vector_type(8)));
typedef float f32x4 __attribute__((ext_vector_type(4)));

// ----------------------------- device scratch ------------------------------
// Interleaved hi/lo K-tile layout: [row][kt][64 shorts] where the 64-short
// block is [hi 32 | lo 32] covering k = kt*32 .. kt*32+31.
__device__ unsigned short g_qw2[(size_t)256 * 8 * 64];    // qw^T * SCALE
__device__ unsigned short g_kvw2[(size_t)512 * 8 * 64];   // kvw^T
__device__ unsigned short g_pw2[(size_t)256 * 8 * 64];    // pw^T
__device__ unsigned short g_wt2[(size_t)256 * 128 * 64];  // conv w^T, kt = tap*8 + ci/32
__device__ unsigned short g_x2[(size_t)32768 * 8 * 64];   // x hi/lo, [b*4096+n][kt][64]
__device__ unsigned short g_ln2[(size_t)2048 * 8 * 64];   // (dead; kept for mgemm_body)
__device__ unsigned short g_q[(size_t)64 * 4096 * 32];    // q bf16, [bh][n][32]
__device__ unsigned short g_k[(size_t)64 * 256 * 32];     // K bf16, [bh][key][32]
__device__ unsigned short g_vt[(size_t)64 * 32 * 256];    // V^T bf16, [bh][d][SLOT] (key-permuted)
__device__ unsigned short g_convp[(size_t)16 * 2048 * 256];  // conv split-K partials (z<4 used)
__device__ unsigned short g_attnb[(size_t)32768 * 256];   // (dead; kept for mgemm_body)

DI float bfbits2f(unsigned short b) { return __uint_as_float(((unsigned)b) << 16); }

DI unsigned short f2bf(float f) {
  unsigned u = __float_as_uint(f);
  unsigned r = (u + 0x7fffu + ((u >> 16) & 1u)) >> 16;
  return (unsigned short)r;
}

DI float4 ld_bf4(const unsigned short* p) {
  ushort4 u = *(const ushort4*)p;
  return make_float4(bfbits2f(u.x), bfbits2f(u.y), bfbits2f(u.z), bfbits2f(u.w));
}

DI float ld1(const void* p, size_t i, int f32) {
  return f32 ? ((const float*)p)[i] : bfbits2f(((const unsigned short*)p)[i]);
}

DI float4 ld4(const void* p, size_t i, int f32) {
  if (f32) return *(const float4*)((const float*)p + i);
  return ld_bf4((const unsigned short*)p + i);
}

// async 16B global -> LDS (dest = wave-uniform base + lane*16; each lane's
// pointer must equal exactly that).
typedef const __attribute__((address_space(1))) void* gas_p;
typedef __attribute__((address_space(3))) void* las_p;
DI void gload16(const unsigned short* g, short* l) {
  __builtin_amdgcn_global_load_lds((gas_p)g, (las_p)l, 16, 0, 0);
}

// counted vmcnt wait (T4): literal strings, fenced.
template <int N> DI void wait_vmcnt() {
  if constexpr (N == 6) asm volatile("s_waitcnt vmcnt(6)" ::: "memory");
  else if constexpr (N == 5) asm volatile("s_waitcnt vmcnt(5)" ::: "memory");
  else if constexpr (N == 4) asm volatile("s_waitcnt vmcnt(4)" ::: "memory");
  else if constexpr (N == 2) asm volatile("s_waitcnt vmcnt(2)" ::: "memory");
  else asm volatile("s_waitcnt vmcnt(0)" ::: "memory");
}

// ---------------------------------------------------------------------------
// Inline dtype detection (see r9 post-mortem: must be the RAW input pointer).
// ---------------------------------------------------------------------------
DI int detect_f32(const void* xp) {
  const unsigned* p = (const unsigned*)xp;
  unsigned m0 = 0, m1 = 0;
#pragma unroll
  for (int i = 0; i < 32; ++i) {
    unsigned w = p[i];
    unsigned lo = w & 0x7fffu, hi = (w >> 16) & 0x7fffu;
    m0 = lo > m0 ? lo : m0;
    m1 = hi > m1 ? hi : m1;
  }
  unsigned mm = m0 > m1 ? m0 : m1;
  return mm >= 0x4680u ? 1 : 0;
}

// ---------------------------------------------------------------------------
// Weight + x prep -> interleaved hi/lo K-tile layout.
// ---------------------------------------------------------------------------
__global__ void k_prep(const void* __restrict__ qw, const void* __restrict__ kvw,
                       const void* __restrict__ pwp, const void* __restrict__ srw,
                       const void* __restrict__ xp) {
  const int f32 = detect_f32(xp);
  int tidg = blockIdx.x * 256 + threadIdx.x;
  float v[8];
  unsigned short* dst;
  if (tidg < 8192) {                       // qw: [o][c] transposed, scaled
    int o = tidg >> 5, w = tidg & 31, k = w * 8;
#pragma unroll
    for (int j = 0; j < 8; ++j) v[j] = ld1(qw, (size_t)(k + j) * 256 + o, f32) * SCALE;
    dst = g_qw2 + ((size_t)o * 8 + (w >> 2)) * 64 + (w & 3) * 8;
  } else if (tidg < 24576) {               // kvw
    int t = tidg - 8192;
    int o = t >> 5, w = t & 31, k = w * 8;
#pragma unroll
    for (int j = 0; j < 8; ++j) v[j] = ld1(kvw, (size_t)(k + j) * 512 + o, f32);
    dst = g_kvw2 + ((size_t)o * 8 + (w >> 2)) * 64 + (w & 3) * 8;
  } else if (tidg < 32768) {               // pw
    int t = tidg - 24576;
    int o = t >> 5, w = t & 31, k = w * 8;
#pragma unroll
    for (int j = 0; j < 8; ++j) v[j] = ld1(pwp, (size_t)(k + j) * 256 + o, f32);
    dst = g_pw2 + ((size_t)o * 8 + (w >> 2)) * 64 + (w & 3) * 8;
  } else if (tidg < 163840) {              // conv w: OIHW -> [o][tap*256+ci]
    int t = tidg - 32768;
    int o = t >> 9, w = t & 511, k = w * 8;
#pragma unroll
    for (int j = 0; j < 8; ++j) {
      int kk = k + j, tap = kk >> 8, ci = kk & 255;
      v[j] = ld1(srw, (size_t)o * 4096 + (size_t)ci * 16 + tap, f32);
    }
    dst = g_wt2 + ((size_t)o * 128 + (w >> 2)) * 64 + (w & 3) * 8;
  } else {                                 // x
    int t = tidg - 163840;
    int m = t >> 5, w = t & 31, k = w * 8;
    size_t base = (size_t)m * 256 + k;
    float4 a = ld4(xp, base, f32);
    float4 b = ld4(xp, base + 4, f32);
    v[0] = a.x; v[1] = a.y; v[2] = a.z; v[3] = a.w;
    v[4] = b.x; v[5] = b.y; v[6] = b.z; v[7] = b.w;
    dst = g_x2 + ((size_t)m * 8 + (w >> 2)) * 64 + (w & 3) * 8;
  }
  ushort4 h0, h1, l0, l1;
  h0.x = f2bf(v[0]); l0.x = f2bf(v[0] - bfbits2f(h0.x));
  h0.y = f2bf(v[1]); l0.y = f2bf(v[1] - bfbits2f(h0.y));
  h0.z = f2bf(v[2]); l0.z = f2bf(v[2] - bfbits2f(h0.z));
  h0.w = f2bf(v[3]); l0.w = f2bf(v[3] - bfbits2f(h0.w));
  h1.x = f2bf(v[4]); l1.x = f2bf(v[4] - bfbits2f(h1.x));
  h1.y = f2bf(v[5]); l1.y = f2bf(v[5] - bfbits2f(h1.y));
  h1.z = f2bf(v[6]); l1.z = f2bf(v[6] - bfbits2f(h1.z));
  h1.w = f2bf(v[7]); l1.w = f2bf(v[7] - bfbits2f(h1.w));
  *(ushort4*)dst        = h0;
  *(ushort4*)(dst + 4)  = h1;
  *(ushort4*)(dst + 32) = l0;
  *(ushort4*)(dst + 36) = l1;
}

// ---------------------------------------------------------------------------
// MFMA GEMM body (modes 0,1 live; 2,3 dead), tile 64 x 128, BK=32.
// DEPTH-2 dbuf global_load_lds pipeline with counted vmcnt (r4/r6-verified).
// MODE 0: A=g_x2,          B=qw2  -> g_q                 NIT=8
// MODE 1: A=g_x2 gathered, B=wt2  -> g_convp[z], z=kh<4  NIT=32 (K=1024)
// ---------------------------------------------------------------------------
template <int MODE>
DI void mgemm_body(short* smem, int bx, int nblk, int z,
                   const void* __restrict__ biasp, void* __restrict__ outp, int f32) {
  constexpr bool AH = (MODE != 3);          // A has a lo part
  constexpr int BN  = (MODE == 2) ? 64 : 128;
  constexpr int NJ  = BN / 64;              // j per wave
  constexpr int NBR = BN / 32;              // B staging rounds
  constexpr int ASZ = AH ? 4096 : 2048;     // shorts
  constexpr int BSZ = NBR * 2048;           // shorts
  constexpr int BUF = ASZ + BSZ;            // shorts per pipeline buffer
  constexpr int NLD = (AH ? 2 : 1) + NBR;   // gloads per thread per iter
  constexpr int NIT = (MODE == 1) ? 32 : 8;
  constexpr int NKT = (MODE == 1) ? 128 : 8;

  const int tid = threadIdx.x;
  const int m0 = bx * 64;
  const int wave = tid >> 6, lane = tid & 63;
  const int quad = lane >> 4, l15 = lane & 15;

  const int srow = tid >> 3;                   // 0..31
  const int slot = (tid & 7) ^ (srow & 7);     // source slot for linear dest

  // ---- per-thread source row bases ----
  size_t arow0 = 0, arow1 = 0, abase3 = 0;
  if constexpr (MODE == 0 || MODE == 2) {
    arow0 = m0 + srow;
    arow1 = m0 + 32 + srow;
  } else if constexpr (MODE == 1) {
    // z = kh; per-iter kw = it>>3 shifts the gathered row by +kw.
#pragma unroll
    for (int r = 0; r < 2; ++r) {
      int m = m0 + r * 32 + srow;
      int bb = m >> 8, sp = m & 255;
      int oh = sp >> 4, ow = sp & 15;
      size_t rb = (size_t)bb * 4096 + (4 * oh + z) * 64 + 4 * ow;
      if (r == 0) arow0 = rb; else arow1 = rb;
    }
  } else {  // MODE 3 (dead)
    int ar = tid >> 2;
    int s3 = (tid & 3) ^ (ar & 3);
    abase3 = (size_t)(m0 + ar) * 256 + s3 * 8;
  }

  const unsigned short* Asrc =
      (MODE == 0 || MODE == 1) ? g_x2 : (MODE == 2) ? g_ln2 : g_attnb;
  const unsigned short* Bsrc = (MODE == 0) ? g_qw2 : (MODE == 1) ? g_wt2
                             : (MODE == 2) ? g_kvw2 : g_pw2;
  const int brow0 = nblk * BN + srow;

  // ---- fragment read offsets (it-invariant, within a buffer) ----
  int aoff[4], boff[NJ];
#pragma unroll
  for (int mt = 0; mt < 4; ++mt) {
    int ar = mt * 16 + l15;
    if constexpr (AH) aoff[mt] = ar * 64 + ((quad ^ (ar & 7)) << 3);
    else              aoff[mt] = ar * 32 + ((quad ^ (ar & 3)) << 3);
  }
#pragma unroll
  for (int j = 0; j < NJ; ++j) {
    int br = wave * (16 * NJ) + j * 16 + l15;
    boff[j] = br * 64 + ((quad ^ (br & 7)) << 3);
  }

  auto STAGE = [&](int it, int b) {
    short* sa = smem + b * BUF;
    short* sb = sa + ASZ;
    if constexpr (MODE == 0 || MODE == 2) {
      gload16(Asrc + (arow0 * 8 + it) * 64 + slot * 8, sa + tid * 8);
      gload16(Asrc + (arow1 * 8 + it) * 64 + slot * 8, sa + 2048 + tid * 8);
    } else if constexpr (MODE == 1) {
      const int kw = it >> 3, ktA = it & 7;
      gload16(Asrc + ((arow0 + kw) * 8 + ktA) * 64 + slot * 8, sa + tid * 8);
      gload16(Asrc + ((arow1 + kw) * 8 + ktA) * 64 + slot * 8, sa + 2048 + tid * 8);
    } else {
      gload16(Asrc + abase3 + (size_t)it * 32, sa + tid * 8);
    }
    const int ktB = (MODE == 1) ? (z * 32 + it) : it;
#pragma unroll
    for (int r = 0; r < NBR; ++r)
      gload16(Bsrc + ((size_t)(brow0 + r * 32) * NKT + ktB) * 64 + slot * 8,
              sb + tid * 8 + r * 2048);
  };

  f32x4 acc[4][NJ] = {};

  auto COMPUTE = [&](int cur) {
    const short* sa = smem + cur * BUF;
    const short* sb = sa + ASZ;
#pragma unroll
    for (int mt = 0; mt < 4; ++mt) {
      bf16x8 a_h = *(const bf16x8*)&sa[aoff[mt]];
      bf16x8 a_l;
      if constexpr (AH) a_l = *(const bf16x8*)&sa[aoff[mt] ^ 32];
#pragma unroll
      for (int j = 0; j < NJ; ++j) {
        bf16x8 b_h = *(const bf16x8*)&sb[boff[j]];
        bf16x8 b_l = *(const bf16x8*)&sb[boff[j] ^ 32];
        f32x4 c = acc[mt][j];
        c = __builtin_amdgcn_mfma_f32_16x16x32_bf16(a_h, b_h, c, 0, 0, 0);
        if constexpr (AH)
          c = __builtin_amdgcn_mfma_f32_16x16x32_bf16(a_l, b_h, c, 0, 0, 0);
        c = __builtin_amdgcn_mfma_f32_16x16x32_bf16(a_h, b_l, c, 0, 0, 0);
        acc[mt][j] = c;
      }
    }
  };

  STAGE(0, 0);
  STAGE(1, 1);
#pragma unroll 1
  for (int it = 0; it < NIT - 1; ++it) {
    const int cur = it & 1;
    wait_vmcnt<NLD>();               // tile t landed; t+1 (+t+2) in flight
    __builtin_amdgcn_s_barrier();
    __builtin_amdgcn_sched_barrier(0);
    COMPUTE(cur);
    asm volatile("" ::: "memory");
    __builtin_amdgcn_s_barrier();    // buf cur fully consumed by all waves
    __builtin_amdgcn_sched_barrier(0);
    if (it < NIT - 2) STAGE(it + 2, cur);   // tile t+2 -> tile t's buffer
  }
  wait_vmcnt<0>();                   // last tile (nothing else in flight)
  __builtin_amdgcn_s_barrier();
  __builtin_amdgcn_sched_barrier(0);
  COMPUTE((NIT - 1) & 1);

  // ---- epilogue ----
  const int f32o = f32;
#pragma unroll
  for (int mt = 0; mt < 4; ++mt) {
#pragma unroll
    for (int j = 0; j < NJ; ++j) {
#pragma unroll
      for (int r = 0; r < 4; ++r) {
        int m = m0 + mt * 16 + quad * 4 + r;
        int c = nblk * BN + wave * (16 * NJ) + j * 16 + l15;
        float v = acc[mt][j][r];
        if constexpr (MODE == 0) {
          int b = m >> 12, n = m & 4095;
          int h = c >> 5, d = c & 31;
          g_q[(((size_t)(b * 8 + h) * 4096 + n) << 5) + d] = f2bf(v);
        } else if constexpr (MODE == 1) {
          g_convp[((size_t)z * 2048 + m) * 256 + c] = f2bf(v);
        } else if constexpr (MODE == 2) {
          int s = c >> 8, h = (c >> 5) & 7, d = c & 31;
          int bb = m >> 8, nk = m & 255;
          if (s == 0) {
            g_k[(((size_t)(bb * 8 + h) * 256 + nk) << 5) + d] = f2bf(v);
          } else {
            int w = nk & 31, cb = nk & ~31;
            int ww = w & 15;
            int vslot = cb + ((ww >> 2) << 3) + ((w >> 4) << 2) + (ww & 3);
            g_vt[(((size_t)(bb * 8 + h) * 32 + d) << 8) + vslot] = f2bf(v);
          }
        } else {
          float rr = v + ld1(biasp, c, f32o);
          if (f32o) ((float*)outp)[(size_t)m * 256 + c] = rr;
          else      ((unsigned short*)outp)[(size_t)m * 256 + c] = f2bf(rr);
        }
      }
    }
  }
}

// Fused conv (first: long 32-iter blocks, round-robin) + q-projection
// (XCD-chunk swizzled so both nb halves of an m-chunk share one XCD's L2).
__launch_bounds__(256, 3)
__global__ void k_mgemm01() {
  __shared__ __align__(16) short smem[2 * 12288];
  int bid = blockIdx.x;
  if (bid < 256) {   // conv: 32 m x 2 nb x 4 z (round-robin -> 32/XCD balanced)
    int m = bid & 31, nb = (bid >> 5) & 1, z = bid >> 6;
    mgemm_body<1>(smem, m, nb, z, nullptr, nullptr, 0);
  } else {           // q: 1024 blocks, bijective chunked swizzle (1024%8==0)
    int bq = bid - 256;
    int lq = (bq & 7) * 128 + (bq >> 3);
    mgemm_body<0>(smem, lq >> 1, lq & 1, 0, nullptr, nullptr, 0);
  }
}

// ---------------------------------------------------------------------------
// FUSED split-K reduce + LayerNorm + kv projection (replaces k_redln +
// old k_mgemm2).  Each block: (1) computes LN for ITS 64 A-rows (8 passes of
// the r11 redln math, bit-identical: same convp loads, same width-32 shuffle
// reduce, same hi/lo split) writing a RESIDENT A-tile in LDS ([64][8kt][8slot]
// with slot ^= row&7, hi slot w^(r7), lo = hi^4 -- the prep/gload convention);
// (2) runs the B-only depth-2 counted-vmcnt K-loop (r10/r11-proven) with
// A read from LDS -- zero A staging.  B(0),B(1) prefetch issued BEFORE the LN
// phase so their latency hides under it.  Kills the k_redln launch and the
// g_ln2 HBM round-trip.  8 nb-duplicate blocks recompute the same LN rows
// (deterministic; convp is L2-resident).  LDS 80 KB -> 2 blocks/CU.
// ---------------------------------------------------------------------------
__launch_bounds__(256, 2)
__global__ void k_mgemm2(const void* __restrict__ xp, const void* __restrict__ srb,
                         const void* __restrict__ lw, const void* __restrict__ lb) {
  __shared__ __align__(16) short smem[32768 + 8192];
  short* sa = smem;            // resident A: LN hi/lo, [64 rows][8 kt][64]
  short* sb = smem + 32768;    // B dbuf: 2 x 4096 shorts

  const int f32 = detect_f32(xp);
  const int tid = threadIdx.x;
  int lq = ((int)blockIdx.x & 7) * 32 + ((int)blockIdx.x >> 3);  // 256%8==0
  const int bx = lq >> 3, nblk = lq & 7;
  const int m0 = bx * 64;

  const int wave = tid >> 6, lane = tid & 63;
  const int quad = lane >> 4, l15 = lane & 15;
  const int srow = tid >> 3;
  const int slot = (tid & 7) ^ (srow & 7);
  const int brow0 = nblk * 64 + srow;

  auto STAGE_B = [&](int it) {
    short* p = sb + (it & 1) * 4096;
#pragma unroll
    for (int r = 0; r < 2; ++r)
      gload16(g_kvw2 + ((size_t)(brow0 + r * 32) * 8 + it) * 64 + slot * 8,
              p + tid * 8 + r * 2048);
  };
  STAGE_B(0);
  STAGE_B(1);

  // ---- LN phase: 8 passes x 8 rows (bit-identical to r11's k_redln) ----
  {
    const int l32 = tid & 31;
    const int ch0 = l32 * 8;
    const int w = l32 & 3, kt = l32 >> 2;
    float4 b0 = ld4(srb, ch0, f32), b1 = ld4(srb, ch0 + 4, f32);
    float4 w0 = ld4(lw, ch0, f32), w1 = ld4(lw, ch0 + 4, f32);
    float4 e0 = ld4(lb, ch0, f32), e1 = ld4(lb, ch0 + 4, f32);
    float bv[8] = {b0.x, b0.y, b0.z, b0.w, b1.x, b1.y, b1.z, b1.w};
    float wv[8] = {w0.x, w0.y, w0.z, w0.w, w1.x, w1.y, w1.z, w1.w};
    float ev[8] = {e0.x, e0.y, e0.z, e0.w, e1.x, e1.y, e1.z, e1.w};
#pragma unroll 1
    for (int pass = 0; pass < 8; ++pass) {
      const int row = pass * 8 + (tid >> 5);
      const size_t idx = (size_t)(m0 + row) * 256 + ch0;
      float c[8] = {};
#pragma unroll
      for (int zz = 0; zz < 4; ++zz) {
        uint4 u = *(const uint4*)&g_convp[(size_t)zz * (2048 * 256) + idx];
        c[0] += __uint_as_float(u.x << 16); c[1] += __uint_as_float(u.x & 0xffff0000u);
        c[2] += __uint_as_float(u.y << 16); c[3] += __uint_as_float(u.y & 0xffff0000u);
        c[4] += __uint_as_float(u.z << 16); c[5] += __uint_as_float(u.z & 0xffff0000u);
        c[6] += __uint_as_float(u.w << 16); c[7] += __uint_as_float(u.w & 0xffff0000u);
      }
#pragma unroll
      for (int j = 0; j < 8; ++j) c[j] += bv[j];
      float s = 0.f, sq = 0.f;
#pragma unroll
      for (int j = 0; j < 8; ++j) { s += c[j]; sq += c[j] * c[j]; }
#pragma unroll
      for (int off = 16; off >= 1; off >>= 1) {
        s += __shfl_xor(s, off, 32);
        sq += __shfl_xor(sq, off, 32);
      }
      float mu = s * (1.0f / 256.0f);
      float var = sq * (1.0f / 256.0f) - mu * mu;
      float rr = rsqrtf(var + 1e-5f);
      float o[8];
#pragma unroll
      for (int j = 0; j < 8; ++j) o[j] = (c[j] - mu) * rr * wv[j] + ev[j];

      ushort4 h0, h1, l0, l1;
      h0.x = f2bf(o[0]); l0.x = f2bf(o[0] - bfbits2f(h0.x));
      h0.y = f2bf(o[1]); l0.y = f2bf(o[1] - bfbits2f(h0.y));
      h0.z = f2bf(o[2]); l0.z = f2bf(o[2] - bfbits2f(h0.z));
      h0.w = f2bf(o[3]); l0.w = f2bf(o[3] - bfbits2f(h0.w));
      h1.x = f2bf(o[4]); l1.x = f2bf(o[4] - bfbits2f(h1.x));
      h1.y = f2bf(o[5]); l1.y = f2bf(o[5] - bfbits2f(h1.y));
      h1.z = f2bf(o[6]); l1.z = f2bf(o[6] - bfbits2f(h1.z));
      h1.w = f2bf(o[7]); l1.w = f2bf(o[7] - bfbits2f(h1.w));

      const int r7 = row & 7;
      short* base = sa + row * 512 + kt * 64;
      const int sh = (w ^ r7) << 3;        // hi slot (w in 0..3 pre-swizzle)
      const int sl = sh ^ 32;              // lo slot = hi^4 (w+4 pre-swizzle)
      *(ushort4*)&base[sh]     = h0;
      *(ushort4*)&base[sh + 4] = h1;
      *(ushort4*)&base[sl]     = l0;
      *(ushort4*)&base[sl + 4] = l1;
    }
  }
  __syncthreads();   // A-tile visible (also drains the B(0),B(1) prefetch)

  // ---- K-loop: B-only depth-2 counted-vmcnt pipeline; A LDS-resident ----
  int aswz[4];
#pragma unroll
  for (int mt = 0; mt < 4; ++mt) {
    int ar = mt * 16 + l15;
    aswz[mt] = ar * 512 + ((quad ^ (ar & 7)) << 3);
  }
  const int br = wave * 16 + l15;
  const int boff = br * 64 + ((quad ^ (br & 7)) << 3);

  f32x4 acc[4] = {};
  auto COMPUTE = [&](int it) {
    const short* sp = sb + (it & 1) * 4096;
#pragma unroll
    for (int mt = 0; mt < 4; ++mt) {
      int ao = aswz[mt] + it * 64;
      bf16x8 a_h = *(const bf16x8*)&sa[ao];
      bf16x8 a_l = *(const bf16x8*)&sa[ao ^ 32];
      bf16x8 b_h = *(const bf16x8*)&sp[boff];
      bf16x8 b_l = *(const bf16x8*)&sp[boff ^ 32];
      f32x4 cc = acc[mt];
      cc = __builtin_amdgcn_mfma_f32_16x16x32_bf16(a_h, b_h, cc, 0, 0, 0);
      cc = __builtin_amdgcn_mfma_f32_16x16x32_bf16(a_l, b_h, cc, 0, 0, 0);
      cc = __builtin_amdgcn_mfma_f32_16x16x32_bf16(a_h, b_l, cc, 0, 0, 0);
      acc[mt] = cc;
    }
  };

#pragma unroll 1
  for (int it = 0; it < 7; ++it) {
    wait_vmcnt<2>();                 // tile t landed; t+1 (+t+2) in flight
    __builtin_amdgcn_s_barrier();
    __builtin_amdgcn_sched_barrier(0);
    COMPUTE(it);
    asm volatile("" ::: "memory");
    __builtin_amdgcn_s_barrier();    // B buf consumed by all waves
    __builtin_amdgcn_sched_barrier(0);
    if (it < 6) STAGE_B(it + 2);
  }
  wait_vmcnt<0>();
  __builtin_amdgcn_s_barrier();
  __builtin_amdgcn_sched_barrier(0);
  COMPUTE(7);

  // ---- epilogue: g_k / g_vt (key-permuted for zero-shuffle PV) ----
#pragma unroll
  for (int mt = 0; mt < 4; ++mt) {
#pragma unroll
    for (int r = 0; r < 4; ++r) {
      int m = m0 + mt * 16 + quad * 4 + r;
      int c = nblk * 64 + wave * 16 + l15;
      float v = acc[mt][r];
      int s = c >> 8, h = (c >> 5) & 7, d = c & 31;
      int bb = m >> 8, nk = m & 255;
      if (s == 0) {
        g_k[(((size_t)(bb * 8 + h) * 256 + nk) << 5) + d] = f2bf(v);
      } else {
        int w = nk & 31, cb = nk & ~31;
        int ww = w & 15;
        int vslot = cb + ((ww >> 2) << 3) + ((w >> 4) << 2) + (ww & 3);
        g_vt[(((size_t)(bb * 8 + h) * 32 + d) << 8) + vslot] = f2bf(v);
      }
    }
  }
}

// ---------------------------------------------------------------------------
// FUSED attention + output projection (r11 structure, unchanged).
// ---------------------------------------------------------------------------
__launch_bounds__(256, 2)
__global__ void k_attnproj(const void* __restrict__ xp, const void* __restrict__ pb,
                           void* __restrict__ outp) {
  __shared__ __align__(16) short smem[16384 + 18688];
  short* att = smem;                 // [64][256] shorts, slot-swizzled
  short* skv = smem + 16384;         // attn: sk(10240)+svt(8448); proj: B dbuf 2x8192

  const int f32o = detect_f32(xp);
  const int tid = threadIdx.x;
  int lq = ((int)blockIdx.x & 7) * 64 + ((int)blockIdx.x >> 3);  // 512%8==0
  const int b = lq >> 6, ntile = lq & 63;

  const int wave = tid >> 6, lane = tid & 63;
  const int quad = lane >> 4, l15 = lane & 15;
  const int rw = wave * 16 + l15;          // row-in-tile
  const int n0g = ntile * 64 + wave * 16;  // global n base for this wave

  short* sk  = skv;            // K [256][40]
  short* svt = skv + 10240;    // V^T [32][264] (key-slot order)

  // prologue: stage head 0 (exposed once per block)
  {
    const uint4* gk = (const uint4*)(g_k + (size_t)(b * 8) * 8192);
    const uint4* gv = (const uint4*)(g_vt + (size_t)(b * 8) * 8192);
    for (int i = tid; i < 1024; i += 256) {
      int key = i >> 2, part = i & 3;
      *(uint4*)&sk[key * 40 + part * 8] = gk[i];
      int d = i >> 5, off = (i & 31) * 8;
      *(uint4*)&svt[d * 264 + off] = gv[i];
    }
  }
  __syncthreads();

  bf16x8 qv = *(const bf16x8*)(g_q + ((size_t)(b * 8) * 4096 + n0g + l15) * 32 + quad * 8);

#pragma unroll 1
  for (int h = 0; h < 8; ++h) {
    const int bh = b * 8 + h;

    f32x4 sacc[16];
    __builtin_amdgcn_s_setprio(1);
#pragma unroll
    for (int t = 0; t < 16; ++t) {
      bf16x8 kf = *(const bf16x8*)&sk[(t * 16 + l15) * 40 + quad * 8];
      f32x4 c = {0.f, 0.f, 0.f, 0.f};
      sacc[t] = __builtin_amdgcn_mfma_f32_16x16x32_bf16(kf, qv, c, 0, 0, 0);
    }
    __builtin_amdgcn_s_setprio(0);

    // ---- T14: issue next head's K/V + q loads NOW (land during softmax+PV)
    uint4 kreg0, kreg1, kreg2, kreg3, vreg0, vreg1, vreg2, vreg3;
    bf16x8 qvn;
    if (h < 7) {
      const uint4* gk = (const uint4*)(g_k + (size_t)(bh + 1) * 8192);
      const uint4* gv = (const uint4*)(g_vt + (size_t)(bh + 1) * 8192);
      kreg0 = gk[tid];       vreg0 = gv[tid];
      kreg1 = gk[tid + 256]; vreg1 = gv[tid + 256];
      kreg2 = gk[tid + 512]; vreg2 = gv[tid + 512];
      kreg3 = gk[tid + 768]; vreg3 = gv[tid + 768];
      qvn = *(const bf16x8*)(g_q + ((size_t)(bh + 1) * 4096 + n0g + l15) * 32 + quad * 8);
    }

    float m = sacc[0][0];
#pragma unroll
    for (int t = 0; t < 16; ++t) {
#pragma unroll
      for (int r = 0; r < 4; ++r) m = fmaxf(m, sacc[t][r]);
    }
    m = fmaxf(m, __shfl_xor(m, 16, 64));
    m = fmaxf(m, __shfl_xor(m, 32, 64));

    unsigned plo[16], phi[16];
    float ls = 0.f;
#pragma unroll
    for (int t = 0; t < 16; ++t) {
      unsigned short p0 = f2bf(__expf(sacc[t][0] - m));
      unsigned short p1 = f2bf(__expf(sacc[t][1] - m));
      unsigned short p2 = f2bf(__expf(sacc[t][2] - m));
      unsigned short p3 = f2bf(__expf(sacc[t][3] - m));
      ls += bfbits2f(p0) + bfbits2f(p1) + bfbits2f(p2) + bfbits2f(p3);
      plo[t] = (unsigned)p0 | ((unsigned)p1 << 16);
      phi[t] = (unsigned)p2 | ((unsigned)p3 << 16);
    }
    ls += __shfl_xor(ls, 16, 64);
    ls += __shfl_xor(ls, 32, 64);
    float inv = 1.0f / ls;

    f32x4 o0 = {0.f, 0.f, 0.f, 0.f}, o1 = {0.f, 0.f, 0.f, 0.f};
    __builtin_amdgcn_s_setprio(1);
#pragma unroll
    for (int c = 0; c < 8; ++c) {
      uint4 pk = make_uint4(plo[2 * c], phi[2 * c], plo[2 * c + 1], phi[2 * c + 1]);
      bf16x8 pf = *(bf16x8*)&pk;
      bf16x8 v0 = *(const bf16x8*)&svt[l15 * 264 + c * 32 + quad * 8];
      bf16x8 v1 = *(const bf16x8*)&svt[(16 + l15) * 264 + c * 32 + quad * 8];
      o0 = __builtin_amdgcn_mfma_f32_16x16x32_bf16(v0, pf, o0, 0, 0, 0);
      o1 = __builtin_amdgcn_mfma_f32_16x16x32_bf16(v1, pf, o1, 0, 0, 0);
    }
    __builtin_amdgcn_s_setprio(0);

    // att LDS write, slot-swizzled: ch0 = h*32 + quad*4, slot = ch0>>3.
    ushort4 u0, u1;
    u0.x = f2bf(o0[0] * inv); u0.y = f2bf(o0[1] * inv);
    u0.z = f2bf(o0[2] * inv); u0.w = f2bf(o0[3] * inv);
    u1.x = f2bf(o1[0] * inv); u1.y = f2bf(o1[1] * inv);
    u1.z = f2bf(o1[2] * inv); u1.w = f2bf(o1[3] * inv);
    int s0 = h * 4 + (quad >> 1);
    int woff = (quad & 1) * 4;
    *(ushort4*)&att[rw * 256 + (((s0    ) ^ (rw & 7)) << 3) + woff] = u0;
    *(ushort4*)&att[rw * 256 + (((s0 + 2) ^ (rw & 7)) << 3) + woff] = u1;

    if (h < 7) {
      __syncthreads();   // drains vmcnt (prefetch regs valid) + barrier
      {
        int key = tid >> 2, part = tid & 3;
        *(uint4*)&sk[key * 40 + part * 8] = kreg0;
        int key1 = (tid + 256) >> 2;
        *(uint4*)&sk[key1 * 40 + part * 8] = kreg1;
        int key2 = (tid + 512) >> 2;
        *(uint4*)&sk[key2 * 40 + part * 8] = kreg2;
        int key3 = (tid + 768) >> 2;
        *(uint4*)&sk[key3 * 40 + part * 8] = kreg3;
        int d0 = tid >> 5, off = (tid & 31) * 8;
        *(uint4*)&svt[d0 * 264 + off] = vreg0;
        *(uint4*)&svt[(d0 + 8) * 264 + off] = vreg1;
        *(uint4*)&svt[(d0 + 16) * 264 + off] = vreg2;
        *(uint4*)&svt[(d0 + 24) * 264 + off] = vreg3;
      }
      qv = qvn;
      __syncthreads();
    } else {
      __syncthreads();   // att visible / skv reusable for proj
    }
  }

  // ---- proj: out[64x256] = att @ pw2 + bias ----
  const int srow = tid >> 3;
  const int slot = (tid & 7) ^ (srow & 7);

  auto STAGE_B = [&](int s) {
    short* sb = skv + (s & 1) * 8192;
    int nb = s >> 3, it = s & 7;
    int brow0 = nb * 128 + srow;
#pragma unroll
    for (int r = 0; r < 4; ++r)
      gload16(g_pw2 + ((size_t)(brow0 + r * 32) * 8 + it) * 64 + slot * 8,
              sb + tid * 8 + r * 2048);
  };

  int boff[2];
#pragma unroll
  for (int j = 0; j < 2; ++j) {
    int br = wave * 32 + j * 16 + l15;
    boff[j] = br * 64 + ((quad ^ (br & 7)) << 3);
  }

  f32x4 accA[4][2] = {};
  f32x4 accB[4][2] = {};

  auto PCOMP = [&](f32x4 (&acc)[4][2], int s) {
    const short* sb = skv + (s & 1) * 8192;
    int it = s & 7;
#pragma unroll
    for (int mt = 0; mt < 4; ++mt) {
      int ar = mt * 16 + l15;
      bf16x8 a_h = *(const bf16x8*)&att[ar * 256 + (((it * 4 + quad) ^ (ar & 7)) << 3)];
#pragma unroll
      for (int j = 0; j < 2; ++j) {
        bf16x8 b_h = *(const bf16x8*)&sb[boff[j]];
        bf16x8 b_l = *(const bf16x8*)&sb[boff[j] ^ 32];
        f32x4 c = acc[mt][j];
        c = __builtin_amdgcn_mfma_f32_16x16x32_bf16(a_h, b_h, c, 0, 0, 0);
        c = __builtin_amdgcn_mfma_f32_16x16x32_bf16(a_h, b_l, c, 0, 0, 0);
        acc[mt][j] = c;
      }
    }
  };

  STAGE_B(0);
  STAGE_B(1);
#pragma unroll 1
  for (int s = 0; s < 8; ++s) {
    wait_vmcnt<4>();
    __builtin_amdgcn_s_barrier();
    __builtin_amdgcn_sched_barrier(0);
    PCOMP(accA, s);
    asm volatile("" ::: "memory");
    __builtin_amdgcn_s_barrier();
    __builtin_amdgcn_sched_barrier(0);
    STAGE_B(s + 2);                 // stages tiles 2..9
  }
#pragma unroll 1
  for (int s = 8; s < 15; ++s) {
    wait_vmcnt<4>();
    __builtin_amdgcn_s_barrier();
    __builtin_amdgcn_sched_barrier(0);
    PCOMP(accB, s);
    asm volatile("" ::: "memory");
    __builtin_amdgcn_s_barrier();
    __builtin_amdgcn_sched_barrier(0);
    if (s < 14) STAGE_B(s + 2);     // stages tiles 10..15
  }
  wait_vmcnt<0>();
  __builtin_amdgcn_s_barrier();
  __builtin_amdgcn_sched_barrier(0);
  PCOMP(accB, 15);

  // all output stores at the end: coalesced burst, outside the vmcnt pipeline
#pragma unroll
  for (int nb = 0; nb < 2; ++nb) {
#pragma unroll
    for (int mt = 0; mt < 4; ++mt) {
#pragma unroll
      for (int j = 0; j < 2; ++j) {
#pragma unroll
        for (int r = 0; r < 4; ++r) {
          int m = ntile * 64 + mt * 16 + quad * 4 + r;
          int c = nb * 128 + wave * 32 + j * 16 + l15;
          float v = (nb == 0 ? accA[mt][j][r] : accB[mt][j][r]) + ld1(pb, c, f32o);
          if (f32o) ((float*)outp)[((size_t)b * 4096 + m) * 256 + c] = v;
          else ((unsigned short*)outp)[((size_t)b * 4096 + m) * 256 + c] = f2bf(v);
        }
      }
    }
  }
}

// ---------------------------------------------------------------------------
extern "C" void kernel_launch(void* const* d_in, const int* in_sizes, int n_in,
                              void* d_out, int out_size, void* d_ws, size_t ws_size,
                              hipStream_t stream) {
  const void* x   = d_in[0];
  const void* qw  = d_in[3];
  const void* kvw = d_in[4];
  const void* srw = d_in[5];
  const void* srb = d_in[6];
  const void* lnw = d_in[7];
  const void* lnb = d_in[8];
  const void* pw  = d_in[9];
  const void* pb  = d_in[10];

  // prep: weights AND x -> interleaved hi/lo K-tile layout
  k_prep<<<4736, 256, 0, stream>>>(qw, kvw, pw, srw, x);
  // fused: conv split-K z=4 (blocks 0-255, 32-iter) + q projection (256-1279)
  k_mgemm01<<<1280, 256, 0, stream>>>();
  // FUSED reduce+LN+kv projection -> g_k / g_vt (V^T key-permuted)
  k_mgemm2<<<256, 256, 0, stream>>>(x, srb, lnw, lnb);
  // FUSED attention + output projection (writes d_out directly)
  k_attnproj<<<512, 256, 0, stream>>>(x, pb, d_out);
}

// Round 13
// 196.766 us; speedup vs baseline: 1.0239x; 1.0239x over previous
//
#include <hip/hip_runtime.h>
#include <hip/hip_bf16.h>
#include <math.h>

#define DI __device__ __forceinline__

static constexpr float SCALE = 0.17677669529663687f;  // 1/sqrt(32)

typedef short bf16x8 __attribute__((ext_vector_type(8)));
typedef float f32x4 __attribute__((ext_vector_type(4)));

// ----------------------------- device scratch ------------------------------
// Interleaved hi/lo K-tile layout: [row][kt][64 shorts] where the 64-short
// block is [hi 32 | lo 32] covering k = kt*32 .. kt*32+31.
__device__ unsigned short g_qw2[(size_t)256 * 8 * 64];    // qw^T * SCALE
__device__ unsigned short g_kvw2[(size_t)512 * 8 * 64];   // kvw^T
__device__ unsigned short g_pw2[(size_t)256 * 8 * 64];    // pw^T
__device__ unsigned short g_wt2[(size_t)256 * 128 * 64];  // conv w^T, kt = tap*8 + ci/32
__device__ unsigned short g_x2[(size_t)32768 * 8 * 64];   // x hi/lo, [b*4096+n][kt][64]
__device__ unsigned short g_ln2[(size_t)2048 * 8 * 64];   // LN out hi/lo
__device__ unsigned short g_q[(size_t)64 * 4096 * 32];    // q bf16, [bh][n][32]
__device__ unsigned short g_k[(size_t)64 * 256 * 32];     // K bf16, [bh][key][32]
__device__ unsigned short g_vt[(size_t)64 * 32 * 256];    // V^T bf16, [bh][d][SLOT] (key-permuted, see k_attnproj)
__device__ unsigned short g_convp[(size_t)16 * 2048 * 256];  // conv split-K partials (z<4 used)
__device__ unsigned short g_attnb[(size_t)32768 * 256];   // (unused; referenced by dead MODE-3 path)

DI float bfbits2f(unsigned short b) { return __uint_as_float(((unsigned)b) << 16); }

DI unsigned short f2bf(float f) {
  unsigned u = __float_as_uint(f);
  unsigned r = (u + 0x7fffu + ((u >> 16) & 1u)) >> 16;
  return (unsigned short)r;
}

DI float4 ld_bf4(const unsigned short* p) {
  ushort4 u = *(const ushort4*)p;
  return make_float4(bfbits2f(u.x), bfbits2f(u.y), bfbits2f(u.z), bfbits2f(u.w));
}

DI float ld1(const void* p, size_t i, int f32) {
  return f32 ? ((const float*)p)[i] : bfbits2f(((const unsigned short*)p)[i]);
}

DI float4 ld4(const void* p, size_t i, int f32) {
  if (f32) return *(const float4*)((const float*)p + i);
  return ld_bf4((const unsigned short*)p + i);
}

// async 16B global -> LDS (dest = wave-uniform base + lane*16; each lane's
// pointer must equal exactly that).
typedef const __attribute__((address_space(1))) void* gas_p;
typedef __attribute__((address_space(3))) void* las_p;
DI void gload16(const unsigned short* g, short* l) {
  __builtin_amdgcn_global_load_lds((gas_p)g, (las_p)l, 16, 0, 0);
}

// counted vmcnt wait (T4): literal strings, fenced.
template <int N> DI void wait_vmcnt() {
  if constexpr (N == 6) asm volatile("s_waitcnt vmcnt(6)" ::: "memory");
  else if constexpr (N == 5) asm volatile("s_waitcnt vmcnt(5)" ::: "memory");
  else if constexpr (N == 4) asm volatile("s_waitcnt vmcnt(4)" ::: "memory");
  else asm volatile("s_waitcnt vmcnt(0)" ::: "memory");
}

// ---------------------------------------------------------------------------
// Inline dtype detection (see r9 post-mortem: must be the RAW input pointer).
// ---------------------------------------------------------------------------
DI int detect_f32(const void* xp) {
  const unsigned* p = (const unsigned*)xp;
  unsigned m0 = 0, m1 = 0;
#pragma unroll
  for (int i = 0; i < 32; ++i) {
    unsigned w = p[i];
    unsigned lo = w & 0x7fffu, hi = (w >> 16) & 0x7fffu;
    m0 = lo > m0 ? lo : m0;
    m1 = hi > m1 ? hi : m1;
  }
  unsigned mm = m0 > m1 ? m0 : m1;
  return mm >= 0x4680u ? 1 : 0;
}

// ---------------------------------------------------------------------------
// Weight + x prep -> interleaved hi/lo K-tile layout.
// ---------------------------------------------------------------------------
__global__ void k_prep(const void* __restrict__ qw, const void* __restrict__ kvw,
                       const void* __restrict__ pwp, const void* __restrict__ srw,
                       const void* __restrict__ xp) {
  const int f32 = detect_f32(xp);
  int tidg = blockIdx.x * 256 + threadIdx.x;
  float v[8];
  unsigned short* dst;
  if (tidg < 8192) {                       // qw: [o][c] transposed, scaled
    int o = tidg >> 5, w = tidg & 31, k = w * 8;
#pragma unroll
    for (int j = 0; j < 8; ++j) v[j] = ld1(qw, (size_t)(k + j) * 256 + o, f32) * SCALE;
    dst = g_qw2 + ((size_t)o * 8 + (w >> 2)) * 64 + (w & 3) * 8;
  } else if (tidg < 24576) {               // kvw
    int t = tidg - 8192;
    int o = t >> 5, w = t & 31, k = w * 8;
#pragma unroll
    for (int j = 0; j < 8; ++j) v[j] = ld1(kvw, (size_t)(k + j) * 512 + o, f32);
    dst = g_kvw2 + ((size_t)o * 8 + (w >> 2)) * 64 + (w & 3) * 8;
  } else if (tidg < 32768) {               // pw
    int t = tidg - 24576;
    int o = t >> 5, w = t & 31, k = w * 8;
#pragma unroll
    for (int j = 0; j < 8; ++j) v[j] = ld1(pwp, (size_t)(k + j) * 256 + o, f32);
    dst = g_pw2 + ((size_t)o * 8 + (w >> 2)) * 64 + (w & 3) * 8;
  } else if (tidg < 163840) {              // conv w: OIHW -> [o][tap*256+ci]
    int t = tidg - 32768;
    int o = t >> 9, w = t & 511, k = w * 8;
#pragma unroll
    for (int j = 0; j < 8; ++j) {
      int kk = k + j, tap = kk >> 8, ci = kk & 255;
      v[j] = ld1(srw, (size_t)o * 4096 + (size_t)ci * 16 + tap, f32);
    }
    dst = g_wt2 + ((size_t)o * 128 + (w >> 2)) * 64 + (w & 3) * 8;
  } else {                                 // x
    int t = tidg - 163840;
    int m = t >> 5, w = t & 31, k = w * 8;
    size_t base = (size_t)m * 256 + k;
    float4 a = ld4(xp, base, f32);
    float4 b = ld4(xp, base + 4, f32);
    v[0] = a.x; v[1] = a.y; v[2] = a.z; v[3] = a.w;
    v[4] = b.x; v[5] = b.y; v[6] = b.z; v[7] = b.w;
    dst = g_x2 + ((size_t)m * 8 + (w >> 2)) * 64 + (w & 3) * 8;
  }
  ushort4 h0, h1, l0, l1;
  h0.x = f2bf(v[0]); l0.x = f2bf(v[0] - bfbits2f(h0.x));
  h0.y = f2bf(v[1]); l0.y = f2bf(v[1] - bfbits2f(h0.y));
  h0.z = f2bf(v[2]); l0.z = f2bf(v[2] - bfbits2f(h0.z));
  h0.w = f2bf(v[3]); l0.w = f2bf(v[3] - bfbits2f(h0.w));
  h1.x = f2bf(v[4]); l1.x = f2bf(v[4] - bfbits2f(h1.x));
  h1.y = f2bf(v[5]); l1.y = f2bf(v[5] - bfbits2f(h1.y));
  h1.z = f2bf(v[6]); l1.z = f2bf(v[6] - bfbits2f(h1.z));
  h1.w = f2bf(v[7]); l1.w = f2bf(v[7] - bfbits2f(h1.w));
  *(ushort4*)dst        = h0;
  *(ushort4*)(dst + 4)  = h1;
  *(ushort4*)(dst + 32) = l0;
  *(ushort4*)(dst + 36) = l1;
}

// ---------------------------------------------------------------------------
// MFMA GEMM body, tile 64(M) x BN(N), BK=32, 256 thr (4 waves).
// BN=128 (modes 0,1: 2 j/wave) or 64 (mode 2: 1 j/wave, 256-block grid).
// DEPTH-2 dbuf global_load_lds pipeline with counted vmcnt (r4/r6-verified).
// MODE 0: A=g_x2,          B=qw2  -> g_q                 NIT=8
// MODE 1: A=g_x2 gathered, B=wt2  -> g_convp[z], z=kh<4  NIT=32 (K=1024)
// MODE 2: A=g_ln2,         B=kvw2 -> g_k + g_vt          NIT=8, BN=64
// ---------------------------------------------------------------------------
template <int MODE>
DI void mgemm_body(short* smem, int bx, int nblk, int z,
                   const void* __restrict__ biasp, void* __restrict__ outp, int f32) {
  constexpr bool AH = (MODE != 3);          // A has a lo part
  constexpr int BN  = (MODE == 2) ? 64 : 128;
  constexpr int NJ  = BN / 64;              // j per wave
  constexpr int NBR = BN / 32;              // B staging rounds
  constexpr int ASZ = AH ? 4096 : 2048;     // shorts
  constexpr int BSZ = NBR * 2048;           // shorts
  constexpr int BUF = ASZ + BSZ;            // shorts per pipeline buffer
  constexpr int NLD = (AH ? 2 : 1) + NBR;   // gloads per thread per iter
  constexpr int NIT = (MODE == 1) ? 32 : 8;
  constexpr int NKT = (MODE == 1) ? 128 : 8;

  const int tid = threadIdx.x;
  const int m0 = bx * 64;
  const int wave = tid >> 6, lane = tid & 63;
  const int quad = lane >> 4, l15 = lane & 15;

  const int srow = tid >> 3;                   // 0..31
  const int slot = (tid & 7) ^ (srow & 7);     // source slot for linear dest

  // ---- per-thread source row bases ----
  size_t arow0 = 0, arow1 = 0, abase3 = 0;
  if constexpr (MODE == 0 || MODE == 2) {
    arow0 = m0 + srow;
    arow1 = m0 + 32 + srow;
  } else if constexpr (MODE == 1) {
    // z = kh; per-iter kw = it>>3 shifts the gathered row by +kw.
#pragma unroll
    for (int r = 0; r < 2; ++r) {
      int m = m0 + r * 32 + srow;
      int bb = m >> 8, sp = m & 255;
      int oh = sp >> 4, ow = sp & 15;
      size_t rb = (size_t)bb * 4096 + (4 * oh + z) * 64 + 4 * ow;
      if (r == 0) arow0 = rb; else arow1 = rb;
    }
  } else {  // MODE 3 (dead)
    int ar = tid >> 2;
    int s3 = (tid & 3) ^ (ar & 3);
    abase3 = (size_t)(m0 + ar) * 256 + s3 * 8;
  }

  const unsigned short* Asrc =
      (MODE == 0 || MODE == 1) ? g_x2 : (MODE == 2) ? g_ln2 : g_attnb;
  const unsigned short* Bsrc = (MODE == 0) ? g_qw2 : (MODE == 1) ? g_wt2
                             : (MODE == 2) ? g_kvw2 : g_pw2;
  const int brow0 = nblk * BN + srow;

  // ---- fragment read offsets (it-invariant, within a buffer) ----
  int aoff[4], boff[NJ];
#pragma unroll
  for (int mt = 0; mt < 4; ++mt) {
    int ar = mt * 16 + l15;
    if constexpr (AH) aoff[mt] = ar * 64 + ((quad ^ (ar & 7)) << 3);
    else              aoff[mt] = ar * 32 + ((quad ^ (ar & 3)) << 3);
  }
#pragma unroll
  for (int j = 0; j < NJ; ++j) {
    int br = wave * (16 * NJ) + j * 16 + l15;
    boff[j] = br * 64 + ((quad ^ (br & 7)) << 3);
  }

  auto STAGE = [&](int it, int b) {
    short* sa = smem + b * BUF;
    short* sb = sa + ASZ;
    if constexpr (MODE == 0 || MODE == 2) {
      gload16(Asrc + (arow0 * 8 + it) * 64 + slot * 8, sa + tid * 8);
      gload16(Asrc + (arow1 * 8 + it) * 64 + slot * 8, sa + 2048 + tid * 8);
    } else if constexpr (MODE == 1) {
      const int kw = it >> 3, ktA = it & 7;
      gload16(Asrc + ((arow0 + kw) * 8 + ktA) * 64 + slot * 8, sa + tid * 8);
      gload16(Asrc + ((arow1 + kw) * 8 + ktA) * 64 + slot * 8, sa + 2048 + tid * 8);
    } else {
      gload16(Asrc + abase3 + (size_t)it * 32, sa + tid * 8);
    }
    const int ktB = (MODE == 1) ? (z * 32 + it) : it;
#pragma unroll
    for (int r = 0; r < NBR; ++r)
      gload16(Bsrc + ((size_t)(brow0 + r * 32) * NKT + ktB) * 64 + slot * 8,
              sb + tid * 8 + r * 2048);
  };

  f32x4 acc[4][NJ] = {};

  auto COMPUTE = [&](int cur) {
    const short* sa = smem + cur * BUF;
    const short* sb = sa + ASZ;
#pragma unroll
    for (int mt = 0; mt < 4; ++mt) {
      bf16x8 a_h = *(const bf16x8*)&sa[aoff[mt]];
      bf16x8 a_l;
      if constexpr (AH) a_l = *(const bf16x8*)&sa[aoff[mt] ^ 32];
#pragma unroll
      for (int j = 0; j < NJ; ++j) {
        bf16x8 b_h = *(const bf16x8*)&sb[boff[j]];
        bf16x8 b_l = *(const bf16x8*)&sb[boff[j] ^ 32];
        f32x4 c = acc[mt][j];
        c = __builtin_amdgcn_mfma_f32_16x16x32_bf16(a_h, b_h, c, 0, 0, 0);
        if constexpr (AH)
          c = __builtin_amdgcn_mfma_f32_16x16x32_bf16(a_l, b_h, c, 0, 0, 0);
        c = __builtin_amdgcn_mfma_f32_16x16x32_bf16(a_h, b_l, c, 0, 0, 0);
        acc[mt][j] = c;
      }
    }
  };

  STAGE(0, 0);
  STAGE(1, 1);
#pragma unroll 1
  for (int it = 0; it < NIT - 1; ++it) {
    const int cur = it & 1;
    wait_vmcnt<NLD>();               // tile t landed; t+1 (+t+2) in flight
    __builtin_amdgcn_s_barrier();
    __builtin_amdgcn_sched_barrier(0);
    COMPUTE(cur);
    asm volatile("" ::: "memory");
    __builtin_amdgcn_s_barrier();    // buf cur fully consumed by all waves
    __builtin_amdgcn_sched_barrier(0);
    if (it < NIT - 2) STAGE(it + 2, cur);   // tile t+2 -> tile t's buffer
  }
  wait_vmcnt<0>();                   // last tile (nothing else in flight)
  __builtin_amdgcn_s_barrier();
  __builtin_amdgcn_sched_barrier(0);
  COMPUTE((NIT - 1) & 1);

  // ---- epilogue (m = m0 + mt*16 + quad*4 + r, n = nblk*BN + wave*16*NJ + j*16 + l15) ----
  const int f32o = f32;
#pragma unroll
  for (int mt = 0; mt < 4; ++mt) {
#pragma unroll
    for (int j = 0; j < NJ; ++j) {
#pragma unroll
      for (int r = 0; r < 4; ++r) {
        int m = m0 + mt * 16 + quad * 4 + r;
        int c = nblk * BN + wave * (16 * NJ) + j * 16 + l15;
        float v = acc[mt][j][r];
        if constexpr (MODE == 0) {
          int b = m >> 12, n = m & 4095;
          int h = c >> 5, d = c & 31;
          g_q[(((size_t)(b * 8 + h) * 4096 + n) << 5) + d] = f2bf(v);
        } else if constexpr (MODE == 1) {
          g_convp[((size_t)z * 2048 + m) * 256 + c] = f2bf(v);
        } else if constexpr (MODE == 2) {
          int s = c >> 8, h = (c >> 5) & 7, d = c & 31;
          int bb = m >> 8, nk = m & 255;
          if (s == 0) {
            g_k[(((size_t)(bb * 8 + h) * 256 + nk) << 5) + d] = f2bf(v);
          } else {
            // V^T stored KEY-PERMUTED (slot = sigma(nk)) so attn's PV
            // B-fragment is the raw QK^T register layout (zero shuffles):
            //   key = 32c + 4q + jj (jj<4 half)  -> slot = 32c + 8q + jj
            //   key = 32c + 16 + 4q + jj         -> slot = 32c + 8q + 4 + jj
            int w = nk & 31, cb = nk & ~31;
            int ww = w & 15;
            int vslot = cb + ((ww >> 2) << 3) + ((w >> 4) << 2) + (ww & 3);
            g_vt[(((size_t)(bb * 8 + h) * 32 + d) << 8) + vslot] = f2bf(v);
          }
        } else {
          float rr = v + ld1(biasp, c, f32o);
          if (f32o) ((float*)outp)[(size_t)m * 256 + c] = rr;
          else      ((unsigned short*)outp)[(size_t)m * 256 + c] = f2bf(rr);
        }
      }
    }
  }
}

// Fused conv (first: long 32-iter blocks, round-robin) + q-projection
// (XCD-chunk swizzled so both nb halves of an m-chunk share one XCD's L2).
__launch_bounds__(256, 3)
__global__ void k_mgemm01() {
  __shared__ __align__(16) short smem[2 * 12288];
  int bid = blockIdx.x;
  if (bid < 256) {   // conv: 32 m x 2 nb x 4 z (round-robin -> 32/XCD balanced)
    int m = bid & 31, nb = (bid >> 5) & 1, z = bid >> 6;
    mgemm_body<1>(smem, m, nb, z, nullptr, nullptr, 0);
  } else {           // q: 1024 blocks, bijective chunked swizzle (1024%8==0)
    int bq = bid - 256;
    int lq = (bq & 7) * 128 + (bq >> 3);
    mgemm_body<0>(smem, lq >> 1, lq & 1, 0, nullptr, nullptr, 0);
  }
}

// kv projection: BN=64 -> 256 blocks (r8 lesson: small GEMMs are TLP-bound).
__launch_bounds__(256, 3)
__global__ void k_mgemm2() {
  __shared__ __align__(16) short smem[2 * 8192];
  int b = blockIdx.x;
  int lq = (b & 7) * 32 + (b >> 3);   // 256%8==0, bijective
  mgemm_body<2>(smem, lq >> 3, lq & 7, 0, nullptr, nullptr, 0);
}

// ---------------------------------------------------------------------------
// Fused split-K reduce (4 partials) + bias + LayerNorm -> g_ln2.
// 8 channels/thread, uint4 loads, width-32 shuffle stats, no LDS.
// ---------------------------------------------------------------------------
__global__ void k_redln(const void* __restrict__ xp, const void* __restrict__ srb,
                        const void* __restrict__ lw, const void* __restrict__ lb) {
  const int f32 = detect_f32(xp);
  const int t = threadIdx.x;
  const int row = blockIdx.x * 8 + (t >> 5);
  const int l32 = t & 31;
  const int ch0 = l32 * 8;
  const size_t idx = (size_t)row * 256 + ch0;

  float c[8] = {};
#pragma unroll
  for (int zz = 0; zz < 4; ++zz) {
    uint4 u = *(const uint4*)&g_convp[(size_t)zz * (2048 * 256) + idx];
    c[0] += __uint_as_float(u.x << 16); c[1] += __uint_as_float(u.x & 0xffff0000u);
    c[2] += __uint_as_float(u.y << 16); c[3] += __uint_as_float(u.y & 0xffff0000u);
    c[4] += __uint_as_float(u.z << 16); c[5] += __uint_as_float(u.z & 0xffff0000u);
    c[6] += __uint_as_float(u.w << 16); c[7] += __uint_as_float(u.w & 0xffff0000u);
  }
  float4 b0 = ld4(srb, ch0, f32), b1 = ld4(srb, ch0 + 4, f32);
  c[0] += b0.x; c[1] += b0.y; c[2] += b0.z; c[3] += b0.w;
  c[4] += b1.x; c[5] += b1.y; c[6] += b1.z; c[7] += b1.w;

  float s = 0.f, sq = 0.f;
#pragma unroll
  for (int j = 0; j < 8; ++j) { s += c[j]; sq += c[j] * c[j]; }
#pragma unroll
  for (int off = 16; off >= 1; off >>= 1) {
    s += __shfl_xor(s, off, 32);
    sq += __shfl_xor(sq, off, 32);
  }
  float mu = s * (1.0f / 256.0f);
  float var = sq * (1.0f / 256.0f) - mu * mu;
  float rr = rsqrtf(var + 1e-5f);

  float4 w0 = ld4(lw, ch0, f32), w1 = ld4(lw, ch0 + 4, f32);
  float4 e0 = ld4(lb, ch0, f32), e1 = ld4(lb, ch0 + 4, f32);
  float wv[8] = {w0.x, w0.y, w0.z, w0.w, w1.x, w1.y, w1.z, w1.w};
  float ev[8] = {e0.x, e0.y, e0.z, e0.w, e1.x, e1.y, e1.z, e1.w};

  float o[8];
#pragma unroll
  for (int j = 0; j < 8; ++j) o[j] = (c[j] - mu) * rr * wv[j] + ev[j];

  ushort4 h0, h1, l0, l1;
  h0.x = f2bf(o[0]); l0.x = f2bf(o[0] - bfbits2f(h0.x));
  h0.y = f2bf(o[1]); l0.y = f2bf(o[1] - bfbits2f(h0.y));
  h0.z = f2bf(o[2]); l0.z = f2bf(o[2] - bfbits2f(h0.z));
  h0.w = f2bf(o[3]); l0.w = f2bf(o[3] - bfbits2f(h0.w));
  h1.x = f2bf(o[4]); l1.x = f2bf(o[4] - bfbits2f(h1.x));
  h1.y = f2bf(o[5]); l1.y = f2bf(o[5] - bfbits2f(h1.y));
  h1.z = f2bf(o[6]); l1.z = f2bf(o[6] - bfbits2f(h1.z));
  h1.w = f2bf(o[7]); l1.w = f2bf(o[7] - bfbits2f(h1.w));

  const size_t dbase = ((size_t)row * 8 + (l32 >> 2)) * 64 + (l32 & 3) * 8;
  *(ushort4*)&g_ln2[dbase]          = h0;
  *(ushort4*)&g_ln2[dbase + 4]      = h1;
  *(ushort4*)&g_ln2[dbase + 32]     = l0;
  *(ushort4*)&g_ln2[dbase + 36]     = l1;
}

// ---------------------------------------------------------------------------
// FUSED attention + output projection.  Block = 64 query rows of one batch;
// loops 8 heads.  (1) T14 async-STAGE for per-head K/V: head h+1's loads are
// issued right after QK^T(h), ds_written at head end -- latency hides under
// softmax+PV.  (2) proj uses dual accumulators so all 64 output stores happen
// after the pipeline (no store-drain stall in the counted-vmcnt loop).
// LDS 70.1 KB -> 2 blocks/CU; grid 512 = 256 CU x 2 exactly.
// ---------------------------------------------------------------------------
__launch_bounds__(256, 2)
__global__ void k_attnproj(const void* __restrict__ xp, const void* __restrict__ pb,
                           void* __restrict__ outp) {
  __shared__ __align__(16) short smem[16384 + 18688];
  short* att = smem;                 // [64][256] shorts, slot-swizzled
  short* skv = smem + 16384;         // attn: sk(10240)+svt(8448); proj: B dbuf 2x8192

  const int f32o = detect_f32(xp);
  const int tid = threadIdx.x;
  int lq = ((int)blockIdx.x & 7) * 64 + ((int)blockIdx.x >> 3);  // 512%8==0
  const int b = lq >> 6, ntile = lq & 63;

  const int wave = tid >> 6, lane = tid & 63;
  const int quad = lane >> 4, l15 = lane & 15;
  const int rw = wave * 16 + l15;          // row-in-tile
  const int n0g = ntile * 64 + wave * 16;  // global n base for this wave

  short* sk  = skv;            // K [256][40]
  short* svt = skv + 10240;    // V^T [32][264] (key-slot order)

  // prologue: stage head 0 (exposed once per block)
  {
    const uint4* gk = (const uint4*)(g_k + (size_t)(b * 8) * 8192);
    const uint4* gv = (const uint4*)(g_vt + (size_t)(b * 8) * 8192);
    for (int i = tid; i < 1024; i += 256) {
      int key = i >> 2, part = i & 3;
      *(uint4*)&sk[key * 40 + part * 8] = gk[i];
      int d = i >> 5, off = (i & 31) * 8;
      *(uint4*)&svt[d * 264 + off] = gv[i];
    }
  }
  __syncthreads();

  bf16x8 qv = *(const bf16x8*)(g_q + ((size_t)(b * 8) * 4096 + n0g + l15) * 32 + quad * 8);

#pragma unroll 1
  for (int h = 0; h < 8; ++h) {
    const int bh = b * 8 + h;

    f32x4 sacc[16];
    __builtin_amdgcn_s_setprio(1);
#pragma unroll
    for (int t = 0; t < 16; ++t) {
      bf16x8 kf = *(const bf16x8*)&sk[(t * 16 + l15) * 40 + quad * 8];
      f32x4 c = {0.f, 0.f, 0.f, 0.f};
      sacc[t] = __builtin_amdgcn_mfma_f32_16x16x32_bf16(kf, qv, c, 0, 0, 0);
    }
    __builtin_amdgcn_s_setprio(0);

    // ---- T14: issue next head's K/V + q loads NOW (land during softmax+PV)
    uint4 kreg0, kreg1, kreg2, kreg3, vreg0, vreg1, vreg2, vreg3;
    bf16x8 qvn;
    if (h < 7) {
      const uint4* gk = (const uint4*)(g_k + (size_t)(bh + 1) * 8192);
      const uint4* gv = (const uint4*)(g_vt + (size_t)(bh + 1) * 8192);
      kreg0 = gk[tid];       vreg0 = gv[tid];
      kreg1 = gk[tid + 256]; vreg1 = gv[tid + 256];
      kreg2 = gk[tid + 512]; vreg2 = gv[tid + 512];
      kreg3 = gk[tid + 768]; vreg3 = gv[tid + 768];
      qvn = *(const bf16x8*)(g_q + ((size_t)(bh + 1) * 4096 + n0g + l15) * 32 + quad * 8);
    }

    float m = sacc[0][0];
#pragma unroll
    for (int t = 0; t < 16; ++t) {
#pragma unroll
      for (int r = 0; r < 4; ++r) m = fmaxf(m, sacc[t][r]);
    }
    m = fmaxf(m, __shfl_xor(m, 16, 64));
    m = fmaxf(m, __shfl_xor(m, 32, 64));

    unsigned plo[16], phi[16];
    float ls = 0.f;
#pragma unroll
    for (int t = 0; t < 16; ++t) {
      unsigned short p0 = f2bf(__expf(sacc[t][0] - m));
      unsigned short p1 = f2bf(__expf(sacc[t][1] - m));
      unsigned short p2 = f2bf(__expf(sacc[t][2] - m));
      unsigned short p3 = f2bf(__expf(sacc[t][3] - m));
      ls += bfbits2f(p0) + bfbits2f(p1) + bfbits2f(p2) + bfbits2f(p3);
      plo[t] = (unsigned)p0 | ((unsigned)p1 << 16);
      phi[t] = (unsigned)p2 | ((unsigned)p3 << 16);
    }
    ls += __shfl_xor(ls, 16, 64);
    ls += __shfl_xor(ls, 32, 64);
    float inv = 1.0f / ls;

    f32x4 o0 = {0.f, 0.f, 0.f, 0.f}, o1 = {0.f, 0.f, 0.f, 0.f};
    __builtin_amdgcn_s_setprio(1);
#pragma unroll
    for (int c = 0; c < 8; ++c) {
      uint4 pk = make_uint4(plo[2 * c], phi[2 * c], plo[2 * c + 1], phi[2 * c + 1]);
      bf16x8 pf = *(bf16x8*)&pk;
      bf16x8 v0 = *(const bf16x8*)&svt[l15 * 264 + c * 32 + quad * 8];
      bf16x8 v1 = *(const bf16x8*)&svt[(16 + l15) * 264 + c * 32 + quad * 8];
      o0 = __builtin_amdgcn_mfma_f32_16x16x32_bf16(v0, pf, o0, 0, 0, 0);
      o1 = __builtin_amdgcn_mfma_f32_16x16x32_bf16(v1, pf, o1, 0, 0, 0);
    }
    __builtin_amdgcn_s_setprio(0);

    // att LDS write, slot-swizzled: ch0 = h*32 + quad*4, slot = ch0>>3.
    ushort4 u0, u1;
    u0.x = f2bf(o0[0] * inv); u0.y = f2bf(o0[1] * inv);
    u0.z = f2bf(o0[2] * inv); u0.w = f2bf(o0[3] * inv);
    u1.x = f2bf(o1[0] * inv); u1.y = f2bf(o1[1] * inv);
    u1.z = f2bf(o1[2] * inv); u1.w = f2bf(o1[3] * inv);
    int s0 = h * 4 + (quad >> 1);
    int woff = (quad & 1) * 4;
    *(ushort4*)&att[rw * 256 + (((s0    ) ^ (rw & 7)) << 3) + woff] = u0;
    *(ushort4*)&att[rw * 256 + (((s0 + 2) ^ (rw & 7)) << 3) + woff] = u1;

    if (h < 7) {
      __syncthreads();   // drains vmcnt (prefetch regs valid) + barrier
      {
        int key = tid >> 2, part = tid & 3;
        *(uint4*)&sk[key * 40 + part * 8] = kreg0;
        int key1 = (tid + 256) >> 2;
        *(uint4*)&sk[key1 * 40 + part * 8] = kreg1;
        int key2 = (tid + 512) >> 2;
        *(uint4*)&sk[key2 * 40 + part * 8] = kreg2;
        int key3 = (tid + 768) >> 2;
        *(uint4*)&sk[key3 * 40 + part * 8] = kreg3;
        int d0 = tid >> 5, off = (tid & 31) * 8;
        *(uint4*)&svt[d0 * 264 + off] = vreg0;
        *(uint4*)&svt[(d0 + 8) * 264 + off] = vreg1;
        *(uint4*)&svt[(d0 + 16) * 264 + off] = vreg2;
        *(uint4*)&svt[(d0 + 24) * 264 + off] = vreg3;
      }
      qv = qvn;
      __syncthreads();
    } else {
      __syncthreads();   // att visible / skv reusable for proj
    }
  }

  // ---- proj: out[64x256] = att @ pw2 + bias ----
  const int srow = tid >> 3;
  const int slot = (tid & 7) ^ (srow & 7);

  auto STAGE_B = [&](int s) {
    short* sb = skv + (s & 1) * 8192;
    int nb = s >> 3, it = s & 7;
    int brow0 = nb * 128 + srow;
#pragma unroll
    for (int r = 0; r < 4; ++r)
      gload16(g_pw2 + ((size_t)(brow0 + r * 32) * 8 + it) * 64 + slot * 8,
              sb + tid * 8 + r * 2048);
  };

  int boff[2];
#pragma unroll
  for (int j = 0; j < 2; ++j) {
    int br = wave * 32 + j * 16 + l15;
    boff[j] = br * 64 + ((quad ^ (br & 7)) << 3);
  }

  f32x4 accA[4][2] = {};
  f32x4 accB[4][2] = {};

  auto PCOMP = [&](f32x4 (&acc)[4][2], int s) {
    const short* sb = skv + (s & 1) * 8192;
    int it = s & 7;
#pragma unroll
    for (int mt = 0; mt < 4; ++mt) {
      int ar = mt * 16 + l15;
      bf16x8 a_h = *(const bf16x8*)&att[ar * 256 + (((it * 4 + quad) ^ (ar & 7)) << 3)];
#pragma unroll
      for (int j = 0; j < 2; ++j) {
        bf16x8 b_h = *(const bf16x8*)&sb[boff[j]];
        bf16x8 b_l = *(const bf16x8*)&sb[boff[j] ^ 32];
        f32x4 c = acc[mt][j];
        c = __builtin_amdgcn_mfma_f32_16x16x32_bf16(a_h, b_h, c, 0, 0, 0);
        c = __builtin_amdgcn_mfma_f32_16x16x32_bf16(a_h, b_l, c, 0, 0, 0);
        acc[mt][j] = c;
      }
    }
  };

  STAGE_B(0);
  STAGE_B(1);
#pragma unroll 1
  for (int s = 0; s < 8; ++s) {
    wait_vmcnt<4>();
    __builtin_amdgcn_s_barrier();
    __builtin_amdgcn_sched_barrier(0);
    PCOMP(accA, s);
    asm volatile("" ::: "memory");
    __builtin_amdgcn_s_barrier();
    __builtin_amdgcn_sched_barrier(0);
    STAGE_B(s + 2);                 // stages tiles 2..9
  }
#pragma unroll 1
  for (int s = 8; s < 15; ++s) {
    wait_vmcnt<4>();
    __builtin_amdgcn_s_barrier();
    __builtin_amdgcn_sched_barrier(0);
    PCOMP(accB, s);
    asm volatile("" ::: "memory");
    __builtin_amdgcn_s_barrier();
    __builtin_amdgcn_sched_barrier(0);
    if (s < 14) STAGE_B(s + 2);     // stages tiles 10..15
  }
  wait_vmcnt<0>();
  __builtin_amdgcn_s_barrier();
  __builtin_amdgcn_sched_barrier(0);
  PCOMP(accB, 15);

  // all output stores at the end: coalesced burst, outside the vmcnt pipeline
#pragma unroll
  for (int nb = 0; nb < 2; ++nb) {
#pragma unroll
    for (int mt = 0; mt < 4; ++mt) {
#pragma unroll
      for (int j = 0; j < 2; ++j) {
#pragma unroll
        for (int r = 0; r < 4; ++r) {
          int m = ntile * 64 + mt * 16 + quad * 4 + r;
          int c = nb * 128 + wave * 32 + j * 16 + l15;
          float v = (nb == 0 ? accA[mt][j][r] : accB[mt][j][r]) + ld1(pb, c, f32o);
          if (f32o) ((float*)outp)[((size_t)b * 4096 + m) * 256 + c] = v;
          else ((unsigned short*)outp)[((size_t)b * 4096 + m) * 256 + c] = f2bf(v);
        }
      }
    }
  }
}

// ---------------------------------------------------------------------------
extern "C" void kernel_launch(void* const* d_in, const int* in_sizes, int n_in,
                              void* d_out, int out_size, void* d_ws, size_t ws_size,
                              hipStream_t stream) {
  const void* x   = d_in[0];
  const void* qw  = d_in[3];
  const void* kvw = d_in[4];
  const void* srw = d_in[5];
  const void* srb = d_in[6];
  const void* lnw = d_in[7];
  const void* lnb = d_in[8];
  const void* pw  = d_in[9];
  const void* pb  = d_in[10];

  // prep: weights AND x -> interleaved hi/lo K-tile layout
  k_prep<<<4736, 256, 0, stream>>>(qw, kvw, pw, srw, x);
  // fused: conv split-K z=4 (blocks 0-255, 32-iter) + q projection (256-1279)
  k_mgemm01<<<1280, 256, 0, stream>>>();
  // fused reduce + bias + LN -> g_ln2
  k_redln<<<256, 256, 0, stream>>>(x, srb, lnw, lnb);
  // kv projection (MFMA, BN=64, 256 blocks) -> g_k / g_vt (V^T key-permuted)
  k_mgemm2<<<256, 256, 0, stream>>>();
  // FUSED attention + output projection (writes d_out directly)
  k_attnproj<<<512, 256, 0, stream>>>(x, pb, d_out);
}